// Round 9
// baseline (160.221 us; speedup 1.0000x reference)
//
#include <hip/hip_runtime.h>

#define N_ROWS 4096
#define TN 8192      // 2N
#define DIM 128
// z is pre-scaled by sqrt(10*log2(e)) so MFMA yields 10*log2e*sim directly:
// exp(10*s) = exp2( (sqrt(c)*zi) . (sqrt(c)*zj) ),  c = 10*log2(e)
#define SQRT_C 3.79828266f

// ws layout: [0,8192) f32 denom | [8192,9216) f32 pos_part | [9216] u32 ticket
//            | z bf16 at byte 40960 (disjoint from ticket — R5 aliased them)
#define Z_BYTE_OFF 40960
#define NBLOCKS_GEMM 4096   // grid (64, 64)

typedef __attribute__((ext_vector_type(8))) short short8;
typedef __attribute__((ext_vector_type(4))) float f32x4;

static __device__ __forceinline__ ushort f2bf(float f) {
    union { float f; unsigned u; } a; a.f = f;
    unsigned r = a.u + 0x7FFF + ((a.u >> 16) & 1);  // round-to-nearest-even
    return (ushort)(r >> 16);
}

// async global->LDS, 16B per lane; LDS dest = wave-uniform base + lane*16 (m104)
static __device__ __forceinline__ void gload_lds16(const void* g, void* l) {
    __builtin_amdgcn_global_load_lds(
        (const __attribute__((address_space(1))) unsigned int*)g,
        (__attribute__((address_space(3))) unsigned int*)l, 16, 0, 0);
}

// --- Kernel A: normalize -> scaled bf16 z; positives partial; zero denom/ticket ---
__global__ __launch_bounds__(256) void prep_kernel(
    const float* __restrict__ anchor, const float* __restrict__ target,
    ushort* __restrict__ z, float* __restrict__ pos_part,
    float* __restrict__ denom, unsigned* __restrict__ ticket)
{
    if (threadIdx.x < 8) denom[blockIdx.x * 8 + threadIdx.x] = 0.0f;
    if (blockIdx.x == 0 && threadIdx.x == 8) *ticket = 0u;

    int wave = threadIdx.x >> 6;
    int lane = threadIdx.x & 63;
    int i    = blockIdx.x * 4 + wave;
    float2 a = ((const float2*)(anchor + (size_t)i * DIM))[lane];
    float2 t = ((const float2*)(target + (size_t)i * DIM))[lane];
    float sa = a.x * a.x + a.y * a.y;
    float st = t.x * t.x + t.y * t.y;
    float dt = a.x * t.x + a.y * t.y;
    #pragma unroll
    for (int m = 1; m < 64; m <<= 1) {
        sa += __shfl_xor(sa, m, 64);
        st += __shfl_xor(st, m, 64);
        dt += __shfl_xor(dt, m, 64);
    }
    float rsa = rsqrtf(fmaxf(sa, 1e-12f));
    float rst = rsqrtf(fmaxf(st, 1e-12f));
    float ka = rsa * SQRT_C, kt = rst * SQRT_C;
    ushort2 za, zt;
    za.x = f2bf(a.x * ka); za.y = f2bf(a.y * ka);
    zt.x = f2bf(t.x * kt); zt.y = f2bf(t.y * kt);
    ((ushort2*)(z + (size_t)i * DIM))[lane] = za;
    ((ushort2*)(z + (size_t)(i + N_ROWS) * DIM))[lane] = zt;
    __shared__ float red[4];
    if (lane == 0) red[wave] = dt * rsa * rst;
    __syncthreads();
    if (threadIdx.x == 0)
        pos_part[blockIdx.x] = red[0] + red[1] + red[2] + red[3];
}

// --- Kernel B: m97-style LDS-staged tile kernel ---
// Block: 128x128 output tile, K=128 one-shot. Stage A-panel (rows) and B-panel
// (cols) of z into LDS via global_load_lds w=16, source pre-XOR-swizzled
// (rule #21: linear LDS dest + swizzled source + same-swizzle read).
// 4 waves 2x2, each computes 64x64: A-frags resident, B per 16-col strip.
__global__ __launch_bounds__(256) void simgemm_kernel(
    const ushort* __restrict__ z, float* __restrict__ denom,
    const float* __restrict__ pos_part, unsigned* __restrict__ ticket,
    float* __restrict__ out)
{
    __shared__ ushort smemA[128 * 128];   // 32 KB
    __shared__ ushort smemB[128 * 128];   // 32 KB

    int wave = threadIdx.x >> 6;
    int lane = threadIdx.x & 63;
    int r = lane & 15;       // A/B row-within-16-tile; C col
    int g = lane >> 4;       // k-group; C row group
    int bx = blockIdx.x, by = blockIdx.y;
    int rowbase = bx * 128, colbase = by * 128;
    const char* zb = (const char*)z;

    // ---- stage both panels: chunk j (1KB) = tile rows 4j..4j+3 ----
    // lane l lands at LDS byte j*1024 + l*16  ->  row 4j+(l>>4), colbyte (l&15)*16.
    // Global source uses colbyte ^ ((row&7)<<4) so a same-XOR read is conflict-free.
    {
        int rsub = lane >> 4;
        int cb   = (lane & 15) << 4;
        #pragma unroll
        for (int i = 0; i < 8; ++i) {
            int j   = (wave << 3) + i;
            int row = (j << 2) + rsub;
            int scb = cb ^ ((row & 7) << 4);
            gload_lds16(zb + (size_t)(rowbase + row) * 256 + scb,
                        (char*)smemA + (j << 10));
            gload_lds16(zb + (size_t)(colbase + row) * 256 + scb,
                        (char*)smemB + (j << 10));
        }
    }
    __syncthreads();   // compiler emits vmcnt(0) drain before barrier

    int wr = wave >> 1, wc = wave & 1;
    const char* sA = (const char*)smemA;
    const char* sB = (const char*)smemB;

    // A fragments: 64 rows x 128 k resident (64 VGPR), pinned vs remat
    short8 a[4][4];
    #pragma unroll
    for (int rt = 0; rt < 4; ++rt)
        #pragma unroll
        for (int kt = 0; kt < 4; ++kt) {
            int row = wr * 64 + rt * 16 + r;
            int cb  = ((kt << 6) + (g << 4)) ^ ((row & 7) << 4);
            a[rt][kt] = *(const short8*)(sA + row * 256 + cb);
            asm volatile("" : "+v"(*(f32x4*)&a[rt][kt]));
        }

    float ps[4][4];
    #pragma unroll
    for (int rt = 0; rt < 4; ++rt)
        #pragma unroll
        for (int q = 0; q < 4; ++q) ps[rt][q] = 0.0f;

    bool wavediag = (bx == by) && (wr == wc);

    #pragma unroll
    for (int ct = 0; ct < 4; ++ct) {
        short8 b[4];
        #pragma unroll
        for (int kt = 0; kt < 4; ++kt) {
            int row = wc * 64 + ct * 16 + r;
            int cb  = ((kt << 6) + (g << 4)) ^ ((row & 7) << 4);
            b[kt] = *(const short8*)(sB + row * 256 + cb);
        }
        if (!wavediag) {
            #pragma unroll
            for (int rt = 0; rt < 4; ++rt) {
                f32x4 acc = {0.f, 0.f, 0.f, 0.f};
                #pragma unroll
                for (int kt = 0; kt < 4; ++kt)
                    acc = __builtin_amdgcn_mfma_f32_16x16x32_bf16(
                        a[rt][kt], b[kt], acc, 0, 0, 0);
                #pragma unroll
                for (int q = 0; q < 4; ++q)
                    ps[rt][q] += __builtin_amdgcn_exp2f(acc[q]);
            }
        } else {
            int gcol = colbase + wc * 64 + ct * 16 + r;
            #pragma unroll
            for (int rt = 0; rt < 4; ++rt) {
                f32x4 acc = {0.f, 0.f, 0.f, 0.f};
                #pragma unroll
                for (int kt = 0; kt < 4; ++kt)
                    acc = __builtin_amdgcn_mfma_f32_16x16x32_bf16(
                        a[rt][kt], b[kt], acc, 0, 0, 0);
                #pragma unroll
                for (int q = 0; q < 4; ++q) {
                    float e = __builtin_amdgcn_exp2f(acc[q]);
                    int grow = rowbase + wr * 64 + rt * 16 + g * 4 + q;
                    ps[rt][q] += (grow == gcol) ? 0.0f : e;
                }
            }
        }
    }

    // reduce across the 16 lanes sharing g, then one atomic per row
    #pragma unroll
    for (int rt = 0; rt < 4; ++rt)
        #pragma unroll
        for (int q = 0; q < 4; ++q) {
            float v = ps[rt][q];
            v += __shfl_xor(v, 1, 64);
            v += __shfl_xor(v, 2, 64);
            v += __shfl_xor(v, 4, 64);
            v += __shfl_xor(v, 8, 64);
            if (r == 0)
                atomicAdd(&denom[rowbase + wr * 64 + rt * 16 + g * 4 + q], v);
        }

    // ---- last-block finalize ----
    __syncthreads();
    __shared__ int islast;
    if (threadIdx.x == 0) {
        __threadfence();
        islast = (atomicAdd(ticket, 1u) == NBLOCKS_GEMM - 1) ? 1 : 0;
    }
    __syncthreads();
    if (islast) {
        int tid = threadIdx.x;
        float slog = 0.0f;
        #pragma unroll
        for (int u = 0; u < TN / 256; ++u) {
            float d = __hip_atomic_load(&denom[u * 256 + tid],
                                        __ATOMIC_RELAXED, __HIP_MEMORY_SCOPE_AGENT);
            slog += logf(d);
        }
        float spos = 0.0f;
        #pragma unroll
        for (int u = 0; u < 1024 / 256; ++u)
            spos += pos_part[u * 256 + tid];
        #pragma unroll
        for (int m = 1; m < 64; m <<= 1) {
            slog += __shfl_xor(slog, m, 64);
            spos += __shfl_xor(spos, m, 64);
        }
        __shared__ float redl[4], redp[4];
        if ((tid & 63) == 0) { redl[tid >> 6] = slog; redp[tid >> 6] = spos; }
        __syncthreads();
        if (tid == 0) {
            float tl = redl[0] + redl[1] + redl[2] + redl[3];
            float tp = redp[0] + redp[1] + redp[2] + redp[3];
            out[0] = (tl - 20.0f * tp) / (float)TN;
        }
    }
}

extern "C" void kernel_launch(void* const* d_in, const int* in_sizes, int n_in,
                              void* d_out, int out_size, void* d_ws, size_t ws_size,
                              hipStream_t stream) {
    const float* anchor = (const float*)d_in[0];
    const float* target = (const float*)d_in[1];
    float* denom       = (float*)d_ws;
    float* pos_part    = denom + TN;                   // 1024 entries
    unsigned* ticket   = (unsigned*)(pos_part + 1024); // float idx 9216
    ushort* z          = (ushort*)((char*)d_ws + Z_BYTE_OFF);

    prep_kernel<<<N_ROWS / 4, 256, 0, stream>>>(anchor, target, z, pos_part,
                                                denom, ticket);
    simgemm_kernel<<<dim3(TN / 128, TN / 128), 256, 0, stream>>>(
        z, denom, pos_part, ticket, (float*)d_out);
}